// Round 9
// baseline (249.327 us; speedup 1.0000x reference)
//
#include <hip/hip_runtime.h>
#include <math.h>

#define NN 8192
#define L2E 1.44269504088896340736f
#define TWO_PI 6.28318530717958647693f

typedef _Float16 h8 __attribute__((ext_vector_type(8)));
typedef float f32x4 __attribute__((ext_vector_type(4)));
#define MFMA16(A, B, C) __builtin_amdgcn_mfma_f32_16x16x32_f16(A, B, C, 0, 0, 0)

union V8 { float4 v[2]; float f[8]; };
union AF { h8 v; decltype(__builtin_amdgcn_cvt_pkrtz(0.f, 0.f)) p[4]; };

// ---------------------------------------------------------------------------
// prep: eta_s=eta*s, phi_s=phi*s (s=sqrt(alpha*log2e)); H1=relu(x@W1+b1)
// f32 row-major + f16 transposed [64][NN]; block 0 zeroes svec and bar.
// ---------------------------------------------------------------------------
__global__ __launch_bounds__(256) void prep_kernel(
    const float* __restrict__ x, const float* __restrict__ alpha,
    const float* __restrict__ W1, const float* __restrict__ b1,
    float* __restrict__ eta_s, float* __restrict__ phi_s,
    float* __restrict__ H1, _Float16* __restrict__ HT1,
    float* __restrict__ svec, unsigned* __restrict__ bar)
{
  __shared__ float sW[448];
  __shared__ float sb[64];
  __shared__ float T[32][65];
  const int t = threadIdx.x;
  if (blockIdx.x == 0) {
    if (t < 64) svec[t] = 0.f;
    if (t == 64) bar[0] = 0u;
  }
  for (int k = t; k < 448; k += 256) sW[k] = W1[k];
  if (t < 64) sb[t] = b1[t];
  const float s = sqrtf(alpha[0] * L2E);
  const int i0 = blockIdx.x * 32;
  const int r = t >> 3, q = t & 7;
  const int i = i0 + r;
  float xv[7];
#pragma unroll
  for (int k = 0; k < 7; k++) xv[k] = x[i * 7 + k];
  if (q == 0) { eta_s[i] = xv[1] * s; phi_s[i] = xv[2] * s; }
  __syncthreads();
#pragma unroll
  for (int c = 0; c < 8; c++) {
    const int n = q * 8 + c;
    float hv = sb[n];
#pragma unroll
    for (int k = 0; k < 7; k++) hv = fmaf(xv[k], sW[k * 64 + n], hv);
    T[r][n] = fmaxf(hv, 0.f);
  }
  __syncthreads();
  for (int e = t; e < 2048; e += 256) H1[i0 * 64 + e] = T[e >> 6][e & 63];
  const int n = t >> 2, sg = (t & 3) * 8;
  h8 v;
#pragma unroll
  for (int ss = 0; ss < 8; ss++) v[ss] = (_Float16)T[sg + ss][n];
  *(h8*)(HT1 + (size_t)n * NN + i0 + sg) = v;
}

// ---------------------------------------------------------------------------
// fused_pass<1>: Y=P@H1 (full j per block) -> U=Y/l+H1 -> Z=relu(U@wt1+bs1)
//                -> H2=relu(Z@W2+b2) -> H2 f32 + HT2 f16-T + lsum.
// fused_pass<2>: Y=P@H2 -> U=Y/l+H2 -> V=relu(U@wt2+bs2) -> col-sums ->
//                atomicAdd svec; last-ticket block computes sigmoid out.
// Block 512 thr = 8 waves, 16 i-rows; wave w streams j in [w*1024,(w+1)*1024)
// with BARRIER-FREE K-loop: B-frags/eta/phi loaded per-lane from L2 (HT is
// 1 MB -> resident in every XCD L2), register prefetch 1 iter ahead, all
// loop loads at compile-time immediate offsets (no address math in loop).
// Grid 512 = 2 blocks/CU.
// ---------------------------------------------------------------------------
template <int PASS>
__global__ __launch_bounds__(512, 4) void fused_pass(
    const float* __restrict__ eta_s, const float* __restrict__ phi_s,
    const _Float16* __restrict__ HTin, const float* __restrict__ Hres,
    const float* __restrict__ WA, const float* __restrict__ bsA,
    const float* __restrict__ WB, const float* __restrict__ bB,
    const float* __restrict__ alpha, float* __restrict__ lsum,
    float* __restrict__ Hout, _Float16* __restrict__ HTout,
    float* __restrict__ svec, const float* __restrict__ Wl,
    const float* __restrict__ bl, float* __restrict__ out,
    unsigned* __restrict__ bar)
{
  __shared__ __align__(16) char smem[46080];
  __shared__ unsigned last_ticket;
  const int tid = threadIdx.x;
  const int w = tid >> 6, lane = tid & 63, m = lane & 15, g = lane >> 4;
  const int i0 = blockIdx.x << 4;
  const float Cs = TWO_PI * sqrtf(alpha[0] * L2E);
  const float et0 = eta_s[i0 + m], ph0 = phi_s[i0 + m];

  const int jw = (w << 10) + (g << 3);
  const _Float16* b0p = HTin + (size_t)(m)      * NN + jw;
  const _Float16* b1p = HTin + (size_t)(16 + m) * NN + jw;
  const _Float16* b2p = HTin + (size_t)(32 + m) * NN + jw;
  const _Float16* b3p = HTin + (size_t)(48 + m) * NN + jw;
  const float* ep = eta_s + jw;
  const float* pp = phi_s + jw;

  f32x4 a0 = {0,0,0,0}, a1 = {0,0,0,0}, a2 = {0,0,0,0}, a3 = {0,0,0,0};
  float lacc = 0.f;

  h8 b0 = *(const h8*)b0p, b1 = *(const h8*)b1p;
  h8 b2 = *(const h8*)b2p, b3 = *(const h8*)b3p;
  V8 E, P;
  E.v[0] = *(const float4*)ep;  E.v[1] = *(const float4*)(ep + 4);
  P.v[0] = *(const float4*)pp;  P.v[1] = *(const float4*)(pp + 4);

#pragma unroll
  for (int it = 0; it < 32; ++it) {
    const h8 cb0 = b0, cb1 = b1, cb2 = b2, cb3 = b3;
    const V8 CE = E, CP = P;
    if (it < 31) {  // compile-time guard (full unroll); immediate offsets
      const int o = (it + 1) * 32;
      b0 = *(const h8*)(b0p + o); b1 = *(const h8*)(b1p + o);
      b2 = *(const h8*)(b2p + o); b3 = *(const h8*)(b3p + o);
      E.v[0] = *(const float4*)(ep + o); E.v[1] = *(const float4*)(ep + o + 4);
      P.v[0] = *(const float4*)(pp + o); P.v[1] = *(const float4*)(pp + o + 4);
    }
    AF af;
#pragma unroll
    for (int tt = 0; tt < 8; tt += 2) {
      float Pv[2];
#pragma unroll
      for (int u = 0; u < 2; ++u) {
        const float dp = ph0 - CP.f[tt + u];
        const float wr = fminf(fabsf(dp), Cs - fabsf(dp));  // abs = modifier
        const float de = et0 - CE.f[tt + u];
        const float r2 = fmaf(de, de, wr * wr);
        const float a  = __builtin_amdgcn_exp2f(-r2);       // neg = modifier
        const float pv = __builtin_amdgcn_exp2f(fmaf(a, L2E, -L2E));
        if constexpr (PASS == 1) lacc += pv;
        Pv[u] = pv;
      }
      af.p[tt >> 1] = __builtin_amdgcn_cvt_pkrtz(Pv[0], Pv[1]);
    }
    a0 = MFMA16(af.v, cb0, a0); a1 = MFMA16(af.v, cb1, a1);
    a2 = MFMA16(af.v, cb2, a2); a3 = MFMA16(af.v, cb3, a3);
  }

  // ---- epilogue: 8-wave Y reduction + row-local GCN transform ----
  float* RED  = (float*)smem;            // [8][16][68] = 34816 B
  float* LRED = (float*)(smem + 34816);  // [32][16]    = 2048 B
  float* LROW = (float*)(smem + 36864);  // [16]
  float* UBUF = (float*)(smem + 37120);  // [16][68]    = 4352 B
  float* ZBUF = (float*)(smem + 41728);  // [16][68]    = 4352 B

  // D layout: col = lane&15, row = g*4 + reg
#pragma unroll
  for (int r = 0; r < 4; ++r) {
    const int rowi = (w * 16 + g * 4 + r) * 68;
    RED[rowi + m]      = a0[r];
    RED[rowi + 16 + m] = a1[r];
    RED[rowi + 32 + m] = a2[r];
    RED[rowi + 48 + m] = a3[r];
  }
  if constexpr (PASS == 1) LRED[((w << 2) | g) * 16 + m] = lacc;
  __syncthreads();

  const int r  = tid >> 5;          // 0..15
  const int c2 = (tid & 31) << 1;   // 0..62 even
  float y0 = 0.f, y1 = 0.f;
#pragma unroll
  for (int q = 0; q < 8; ++q) {
    y0 += RED[(q * 16 + r) * 68 + c2];
    y1 += RED[(q * 16 + r) * 68 + c2 + 1];
  }
  const float2 hres = *(const float2*)(Hres + (size_t)(i0 + r) * 64 + c2);
  if (tid < 16) {
    float lv;
    if constexpr (PASS == 1) {
      lv = 0.f;
#pragma unroll
      for (int q = 0; q < 32; ++q) lv += LRED[q * 16 + tid];
      lsum[i0 + tid] = lv;
    } else {
      lv = lsum[i0 + tid];
    }
    LROW[tid] = lv;
  }
  __syncthreads();

  const float rl = 1.0f / LROW[r];
  UBUF[r * 68 + c2]     = fmaf(y0, rl, hres.x);
  UBUF[r * 68 + c2 + 1] = fmaf(y1, rl, hres.y);
  __syncthreads();

  // Z = relu(U @ WA + bsA[0])
  float z0 = bsA[0], z1 = z0;
  for (int k = 0; k < 64; ++k) {
    const float uk = UBUF[r * 68 + k];
    const float2 wv = *(const float2*)(WA + k * 64 + c2);
    z0 = fmaf(uk, wv.x, z0);
    z1 = fmaf(uk, wv.y, z1);
  }
  z0 = fmaxf(z0, 0.f); z1 = fmaxf(z1, 0.f);
  ZBUF[r * 68 + c2]     = z0;
  ZBUF[r * 68 + c2 + 1] = z1;
  __syncthreads();

  if constexpr (PASS == 1) {
    // H2 = relu(Z @ WB + bB)
    float h0 = bB[c2], h1 = bB[c2 + 1];
    for (int k = 0; k < 64; ++k) {
      const float zk = ZBUF[r * 68 + k];
      const float2 wv = *(const float2*)(WB + k * 64 + c2);
      h0 = fmaf(zk, wv.x, h0);
      h1 = fmaf(zk, wv.y, h1);
    }
    h0 = fmaxf(h0, 0.f); h1 = fmaxf(h1, 0.f);
    float2 hw; hw.x = h0; hw.y = h1;
    *(float2*)(Hout + (size_t)(i0 + r) * 64 + c2) = hw;
    UBUF[r * 68 + c2]     = h0;
    UBUF[r * 68 + c2 + 1] = h1;
    __syncthreads();
    const int n = tid >> 3, ri = (tid & 7) << 1;
    union { _Float16 hh[2]; unsigned u; } pk;
    pk.hh[0] = (_Float16)UBUF[ri * 68 + n];
    pk.hh[1] = (_Float16)UBUF[(ri + 1) * 68 + n];
    *(unsigned*)(HTout + (size_t)n * NN + i0 + ri) = pk.u;
  } else {
    if (tid < 64) {
      float cs = 0.f;
#pragma unroll
      for (int rw = 0; rw < 16; ++rw) cs += ZBUF[rw * 68 + tid];
      atomicAdd(svec + tid, cs);
    }
    __syncthreads();
    if (tid == 0)
      last_ticket = __hip_atomic_fetch_add(bar, 1u, __ATOMIC_RELAXED,
                                           __HIP_MEMORY_SCOPE_AGENT);
    __syncthreads();
    if (last_ticket == gridDim.x - 1) {
      if (tid == 0) __builtin_amdgcn_fence(__ATOMIC_ACQUIRE, "agent");
      __syncthreads();
      if (tid < 64) {
        float v = svec[tid] * Wl[tid];
#pragma unroll
        for (int off = 32; off > 0; off >>= 1) v += __shfl_down(v, off);
        if (tid == 0) {
          const float logit = v + bl[0];
          out[0] = 1.0f / (1.0f + __builtin_amdgcn_exp2f(-logit * L2E));
        }
      }
    }
  }
}

extern "C" void kernel_launch(void* const* d_in, const int* in_sizes, int n_in,
                              void* d_out, int out_size, void* d_ws,
                              size_t ws_size, hipStream_t stream)
{
  const float* x     = (const float*)d_in[0];
  const float* alpha = (const float*)d_in[1];
  const float* W1    = (const float*)d_in[2];
  const float* b1    = (const float*)d_in[3];
  const float* wt1   = (const float*)d_in[4];
  const float* bs1   = (const float*)d_in[5];
  const float* W2    = (const float*)d_in[6];
  const float* b2    = (const float*)d_in[7];
  const float* wt2   = (const float*)d_in[8];
  const float* bs2   = (const float*)d_in[9];
  const float* Wl    = (const float*)d_in[10];
  const float* bl    = (const float*)d_in[11];
  float* out = (float*)d_out;

  char* ws = (char*)d_ws;
  size_t off = 0;
  auto alloc = [&](size_t bytes) {
    void* p = ws + off;
    off = (off + bytes + 255) & ~(size_t)255;
    return p;
  };
  float* eta_s   = (float*)alloc(NN * 4 + 512);
  float* phi_s   = (float*)alloc(NN * 4 + 512);
  float* H1      = (float*)alloc((size_t)NN * 64 * 4);
  float* H2      = (float*)alloc((size_t)NN * 64 * 4);
  _Float16* HT1  = (_Float16*)alloc((size_t)NN * 64 * 2 + 512);
  _Float16* HT2  = (_Float16*)alloc((size_t)NN * 64 * 2 + 512);
  float* lsum    = (float*)alloc(NN * 4);
  float* svec    = (float*)alloc(64 * 4);
  unsigned* bar  = (unsigned*)alloc(256);

  prep_kernel<<<256, 256, 0, stream>>>(x, alpha, W1, b1, eta_s, phi_s, H1,
                                       HT1, svec, bar);
  fused_pass<1><<<512, 512, 0, stream>>>(eta_s, phi_s, HT1, H1, wt1, bs1, W2,
                                         b2, alpha, lsum, H2, HT2, nullptr,
                                         nullptr, nullptr, nullptr, nullptr);
  fused_pass<2><<<512, 512, 0, stream>>>(eta_s, phi_s, HT2, H2, wt2, bs2,
                                         nullptr, nullptr, alpha, lsum,
                                         nullptr, nullptr, svec, Wl, bl, out,
                                         bar);
}

// Round 10
// 194.770 us; speedup vs baseline: 1.2801x; 1.2801x over previous
//
#include <hip/hip_runtime.h>
#include <math.h>

#define NN 8192
#define L2E 1.44269504088896340736f
#define TWO_PI 6.28318530717958647693f

typedef _Float16 h8 __attribute__((ext_vector_type(8)));
typedef float f32x4 __attribute__((ext_vector_type(4)));
#define MFMA16(A, B, C) __builtin_amdgcn_mfma_f32_16x16x32_f16(A, B, C, 0, 0, 0)

// async 16B-per-lane global->LDS DMA; LDS dest is wave-uniform base + lane*16
#define GLD_LDS16(gsrc, ldst)                                          \
  __builtin_amdgcn_global_load_lds(                                    \
      (const __attribute__((address_space(1))) unsigned int*)(gsrc),   \
      (__attribute__((address_space(3))) unsigned int*)(ldst), 16, 0, 0)

union V8 { float4 v[2]; float f[8]; };
union AF { h8 v; decltype(__builtin_amdgcn_cvt_pkrtz(0.f, 0.f)) p[4]; };

// ---------------------------------------------------------------------------
// prep: eta_s/phi_s pre-scaled; H1 = relu(x@W1+b1) f32 + f16-T; zero all
// accumulators/tickets (ws is poisoned 0xAA before every call). 32 rows/blk.
// ---------------------------------------------------------------------------
__global__ __launch_bounds__(256) void prep_kernel(
    const float* __restrict__ x, const float* __restrict__ alpha,
    const float* __restrict__ W1, const float* __restrict__ b1,
    float* __restrict__ eta_s, float* __restrict__ phi_s,
    float* __restrict__ H1, _Float16* __restrict__ HT1,
    float* __restrict__ lsum, float* __restrict__ Yacc1,
    float* __restrict__ Yacc2, float* __restrict__ svec,
    unsigned* __restrict__ tick1, unsigned* __restrict__ tick2,
    unsigned* __restrict__ bar)
{
  __shared__ float sW[448];
  __shared__ float sb[64];
  __shared__ float T[32][65];
  const int t = threadIdx.x;
  const int b = blockIdx.x;
  // zero accumulators: 2048 floats of each Yacc per block (8/thread)
  {
    const float4 z4 = {0.f, 0.f, 0.f, 0.f};
#pragma unroll
    for (int k = 0; k < 2; ++k) {
      *(float4*)(Yacc1 + (size_t)b * 2048 + ((k * 256 + t) << 2)) = z4;
      *(float4*)(Yacc2 + (size_t)b * 2048 + ((k * 256 + t) << 2)) = z4;
    }
    if (t < 32) lsum[b * 32 + t] = 0.f;
    if (b == 0) {
      tick1[t] = 0u; tick2[t] = 0u;
      if (t < 64) svec[t] = 0.f;
      if (t == 0) bar[0] = 0u;
    }
  }
  for (int k = t; k < 448; k += 256) sW[k] = W1[k];
  if (t < 64) sb[t] = b1[t];
  const float s = sqrtf(alpha[0] * L2E);
  const int i0 = b * 32;
  const int r = t >> 3, q = t & 7;
  const int i = i0 + r;
  float xv[7];
#pragma unroll
  for (int k = 0; k < 7; k++) xv[k] = x[i * 7 + k];
  if (q == 0) { eta_s[i] = xv[1] * s; phi_s[i] = xv[2] * s; }
  __syncthreads();
#pragma unroll
  for (int c = 0; c < 8; c++) {
    const int n = q * 8 + c;
    float hv = sb[n];
#pragma unroll
    for (int k = 0; k < 7; k++) hv = fmaf(xv[k], sW[k * 64 + n], hv);
    T[r][n] = fmaxf(hv, 0.f);
  }
  __syncthreads();
  for (int e = t; e < 2048; e += 256) H1[i0 * 64 + e] = T[e >> 6][e & 63];
  const int n = t >> 2, sg = (t & 3) * 8;
  h8 v;
#pragma unroll
  for (int ss = 0; ss < 8; ss++) v[ss] = (_Float16)T[sg + ss][n];
  *(h8*)(HT1 + (size_t)n * NN + i0 + sg) = v;
}

// ---------------------------------------------------------------------------
// fused_pass: R5's proven attn K-loop (32 i-rows, 4-way j-split, grid 1024,
// 256 thr, DMA-staged double-buffered LDS) + atomicAdd-combined epilogue:
// the 4 blocks of a tile atomicAdd partial Y/l; last-ticket block runs the
// row transform. PASS1: U->Z->H2 (+f16-T). PASS2: U->Z->colsum->svec; global
// last-of-256 ticket computes sigmoid out. Losers exit early.
// ---------------------------------------------------------------------------
template <int PASS>
__global__ __launch_bounds__(256, 4) void fused_pass(
    const float* __restrict__ eta_s, const float* __restrict__ phi_s,
    const _Float16* __restrict__ HTin, const float* __restrict__ Hres,
    const float* __restrict__ WA, const float* __restrict__ bsA,
    const float* __restrict__ WB, const float* __restrict__ bB,
    const float* __restrict__ alpha, float* __restrict__ lsum,
    float* __restrict__ Yacc, float* __restrict__ Hout,
    _Float16* __restrict__ HTout, float* __restrict__ svec,
    const float* __restrict__ Wl, const float* __restrict__ bl,
    float* __restrict__ out, unsigned* __restrict__ tick,
    unsigned* __restrict__ bar)
{
  __shared__ __align__(16) char smem[33792];
  __shared__ unsigned last;
  _Float16* stage = (_Float16*)smem;  // 2 x 16384 B
  const int tid = threadIdx.x;
  const int w = tid >> 6, lane = tid & 63, m = lane & 15, g = lane >> 4;
  const int tile = blockIdx.x >> 2, part = blockIdx.x & 3;
  const int i0 = tile << 5;
  const int jbase = part << 11;
  const float Cs = TWO_PI * sqrtf(alpha[0] * L2E);
  const float et0 = eta_s[i0 + m],      ph0 = phi_s[i0 + m];
  const float et1 = eta_s[i0 + 16 + m], ph1 = phi_s[i0 + 16 + m];

  const int r0 = tid >> 4, gq = tid & 15;
  const _Float16* sbase = HTin + (size_t)r0 * NN + ((gq ^ r0) << 3) + jbase;

  f32x4 a00 = {0,0,0,0}, a01 = {0,0,0,0}, a02 = {0,0,0,0}, a03 = {0,0,0,0};
  f32x4 a10 = {0,0,0,0}, a11 = {0,0,0,0}, a12 = {0,0,0,0}, a13 = {0,0,0,0};
  float l0 = 0.f, l1 = 0.f;

  const float* ep = eta_s + jbase + (w << 5) + (g << 3);
  const float* pp = phi_s + jbase + (w << 5) + (g << 3);
  V8 E, P, En, Pn;
  E.v[0] = *(const float4*)ep;  E.v[1] = *(const float4*)(ep + 4);
  P.v[0] = *(const float4*)pp;  P.v[1] = *(const float4*)(pp + 4);
  En = E; Pn = P;

#pragma unroll
  for (int k = 0; k < 4; ++k)
    GLD_LDS16(sbase + (size_t)k * 16 * NN, stage + ((k * 256 + tid) << 3));
  __syncthreads();

  const int fs = ((m << 4) + (((w << 2) | g) ^ m)) << 3;

  for (int s = 0; s < 16; ++s) {
    _Float16* cur = stage + ((s & 1) << 13);
    if (s < 15) {
      _Float16* nxt = stage + (((s + 1) & 1) << 13);
      const _Float16* srcp = sbase + (s + 1) * 128;
#pragma unroll
      for (int k = 0; k < 4; ++k)
        GLD_LDS16(srcp + (size_t)k * 16 * NN, nxt + ((k * 256 + tid) << 3));
      En.v[0] = *(const float4*)(ep + 128); En.v[1] = *(const float4*)(ep + 132);
      Pn.v[0] = *(const float4*)(pp + 128); Pn.v[1] = *(const float4*)(pp + 132);
      ep += 128; pp += 128;
    }
    const h8 b0 = *(const h8*)(cur + fs);
    const h8 b1 = *(const h8*)(cur + 2048 + fs);
    const h8 b2 = *(const h8*)(cur + 4096 + fs);
    const h8 b3 = *(const h8*)(cur + 6144 + fs);

    AF af0, af1;
#pragma unroll
    for (int tt = 0; tt < 8; tt += 2) {
      float Pv[4];
#pragma unroll
      for (int u = 0; u < 2; ++u) {
        {
          const float dp = ph0 - P.f[tt + u];
          const float ad = fabsf(dp);
          const float wr = fminf(ad, Cs - ad);
          const float de = et0 - E.f[tt + u];
          const float r2 = fmaf(de, de, wr * wr);
          const float a  = __builtin_amdgcn_exp2f(-r2);
          const float pv = __builtin_amdgcn_exp2f(fmaf(a, L2E, -L2E));
          if constexpr (PASS == 1) l0 += pv;
          Pv[u] = pv;
        }
        {
          const float dp = ph1 - P.f[tt + u];
          const float ad = fabsf(dp);
          const float wr = fminf(ad, Cs - ad);
          const float de = et1 - E.f[tt + u];
          const float r2 = fmaf(de, de, wr * wr);
          const float a  = __builtin_amdgcn_exp2f(-r2);
          const float pv = __builtin_amdgcn_exp2f(fmaf(a, L2E, -L2E));
          if constexpr (PASS == 1) l1 += pv;
          Pv[2 + u] = pv;
        }
      }
      af0.p[tt >> 1] = __builtin_amdgcn_cvt_pkrtz(Pv[0], Pv[1]);
      af1.p[tt >> 1] = __builtin_amdgcn_cvt_pkrtz(Pv[2], Pv[3]);
    }
    a00 = MFMA16(af0.v, b0, a00); a01 = MFMA16(af0.v, b1, a01);
    a02 = MFMA16(af0.v, b2, a02); a03 = MFMA16(af0.v, b3, a03);
    a10 = MFMA16(af1.v, b0, a10); a11 = MFMA16(af1.v, b1, a11);
    a12 = MFMA16(af1.v, b2, a12); a13 = MFMA16(af1.v, b3, a13);
    E = En; P = Pn;
    __syncthreads();
  }

  // 4-wave LDS reduction (R5). D layout: col=lane&15, row=(lane>>4)*4+reg.
  typedef float Red2[32][66];
  Red2* red = (Red2*)smem;
  float* lredF = (float*)(smem + 32768);
  const int h = w >> 1;
  if ((w & 1) == 0) {
#pragma unroll
    for (int r = 0; r < 4; ++r) {
      red[h][g * 4 + r][m]      = a00[r]; red[h][g * 4 + r][16 + m] = a01[r];
      red[h][g * 4 + r][32 + m] = a02[r]; red[h][g * 4 + r][48 + m] = a03[r];
      red[h][16 + g * 4 + r][m]      = a10[r]; red[h][16 + g * 4 + r][16 + m] = a11[r];
      red[h][16 + g * 4 + r][32 + m] = a12[r]; red[h][16 + g * 4 + r][48 + m] = a13[r];
    }
    if constexpr (PASS == 1) {
      lredF[h * 128 + g * 32 + m] = l0; lredF[h * 128 + g * 32 + 16 + m] = l1;
    }
  }
  __syncthreads();
  if (w & 1) {
#pragma unroll
    for (int r = 0; r < 4; ++r) {
      red[h][g * 4 + r][m]      += a00[r]; red[h][g * 4 + r][16 + m] += a01[r];
      red[h][g * 4 + r][32 + m] += a02[r]; red[h][g * 4 + r][48 + m] += a03[r];
      red[h][16 + g * 4 + r][m]      += a10[r]; red[h][16 + g * 4 + r][16 + m] += a11[r];
      red[h][16 + g * 4 + r][32 + m] += a12[r]; red[h][16 + g * 4 + r][48 + m] += a13[r];
    }
    if constexpr (PASS == 1) {
      lredF[h * 128 + g * 32 + m] += l0; lredF[h * 128 + g * 32 + 16 + m] += l1;
    }
  }
  __syncthreads();

  // combine across the 4 part-blocks via device atomics
#pragma unroll
  for (int k = 0; k < 8; ++k) {
    const int e = tid + (k << 8);
    atomicAdd(Yacc + (((size_t)(i0 + (e >> 6))) << 6) + (e & 63),
              red[0][e >> 6][e & 63] + red[1][e >> 6][e & 63]);
  }
  if constexpr (PASS == 1) {
    if (tid < 32) {
      float sv = 0.f;
#pragma unroll
      for (int hh = 0; hh < 2; ++hh)
#pragma unroll
        for (int gg = 0; gg < 4; ++gg) sv += lredF[hh * 128 + gg * 32 + tid];
      atomicAdd(lsum + i0 + tid, sv);
    }
  }
  __syncthreads();  // drains atomics (vmcnt) before ticket
  if (tid == 0)
    last = __hip_atomic_fetch_add(tick + tile, 1u, __ATOMIC_RELAXED,
                                  __HIP_MEMORY_SCOPE_AGENT);
  __syncthreads();
  if (last != 3) return;  // losers exit early
  if (tid == 0) __builtin_amdgcn_fence(__ATOMIC_ACQUIRE, "agent");
  __syncthreads();

  // ---- winner: row transform for rows i0..i0+31 ----
  float* UBUF = (float*)smem;            // [32][68]
  float* ZBUF = (float*)(smem + 8704);   // [32][68]
  float* LROW = (float*)(smem + 17408);  // [32]
  const int r  = tid >> 3;
  const int c0 = (tid & 7) << 3;
  if (tid < 32) LROW[tid] = lsum[i0 + tid];
  __syncthreads();
  const float rl = 1.0f / LROW[r];
  {
    const size_t rowb = ((size_t)(i0 + r)) << 6;
    const f32x4 ya = *(const f32x4*)(Yacc + rowb + c0);
    const f32x4 yb = *(const f32x4*)(Yacc + rowb + c0 + 4);
    const f32x4 ha = *(const f32x4*)(Hres + rowb + c0);
    const f32x4 hb = *(const f32x4*)(Hres + rowb + c0 + 4);
#pragma unroll
    for (int c = 0; c < 4; ++c) {
      UBUF[r * 68 + c0 + c]     = fmaf(ya[c], rl, ha[c]);
      UBUF[r * 68 + c0 + 4 + c] = fmaf(yb[c], rl, hb[c]);
    }
  }
  __syncthreads();
  float z[8];
  const float bz = bsA[0];
#pragma unroll
  for (int c = 0; c < 8; ++c) z[c] = bz;
  for (int k = 0; k < 64; ++k) {
    const float uk = UBUF[r * 68 + k];
    const f32x4 wa = *(const f32x4*)(WA + (k << 6) + c0);
    const f32x4 wb = *(const f32x4*)(WA + (k << 6) + c0 + 4);
#pragma unroll
    for (int c = 0; c < 4; ++c) {
      z[c]     = fmaf(uk, wa[c], z[c]);
      z[4 + c] = fmaf(uk, wb[c], z[4 + c]);
    }
  }
#pragma unroll
  for (int c = 0; c < 8; ++c) ZBUF[r * 68 + c0 + c] = fmaxf(z[c], 0.f);
  __syncthreads();

  if constexpr (PASS == 1) {
    float hh[8];
#pragma unroll
    for (int c = 0; c < 8; ++c) hh[c] = bB[c0 + c];
    for (int k = 0; k < 64; ++k) {
      const float zk = ZBUF[r * 68 + k];
      const f32x4 wa = *(const f32x4*)(WB + (k << 6) + c0);
      const f32x4 wb = *(const f32x4*)(WB + (k << 6) + c0 + 4);
#pragma unroll
      for (int c = 0; c < 4; ++c) {
        hh[c]     = fmaf(zk, wa[c], hh[c]);
        hh[4 + c] = fmaf(zk, wb[c], hh[4 + c]);
      }
    }
    f32x4 ha, hb2;
#pragma unroll
    for (int c = 0; c < 4; ++c) {
      ha[c]  = fmaxf(hh[c], 0.f);
      hb2[c] = fmaxf(hh[4 + c], 0.f);
    }
    const size_t rowb = ((size_t)(i0 + r)) << 6;
    *(f32x4*)(Hout + rowb + c0)     = ha;
    *(f32x4*)(Hout + rowb + c0 + 4) = hb2;
#pragma unroll
    for (int c = 0; c < 4; ++c) {
      UBUF[r * 68 + c0 + c]     = ha[c];
      UBUF[r * 68 + c0 + 4 + c] = hb2[c];
    }
    __syncthreads();
    const int n = tid >> 2, ri = (tid & 3) << 3;
    h8 v;
#pragma unroll
    for (int ss = 0; ss < 8; ++ss) v[ss] = (_Float16)UBUF[(ri + ss) * 68 + n];
    *(h8*)(HTout + (size_t)n * NN + i0 + ri) = v;
  } else {
    if (tid < 64) {
      float cs = 0.f;
#pragma unroll
      for (int rw = 0; rw < 32; ++rw) cs += ZBUF[rw * 68 + tid];
      atomicAdd(svec + tid, cs);
    }
    __syncthreads();  // drains svec atomics before the global ticket
    if (tid == 0)
      last = __hip_atomic_fetch_add(bar, 1u, __ATOMIC_RELAXED,
                                    __HIP_MEMORY_SCOPE_AGENT);
    __syncthreads();
    if (last == (gridDim.x >> 2) - 1) {
      if (tid == 0) __builtin_amdgcn_fence(__ATOMIC_ACQUIRE, "agent");
      __syncthreads();
      if (tid < 64) {
        float v = svec[tid] * Wl[tid];
#pragma unroll
        for (int off = 32; off > 0; off >>= 1) v += __shfl_down(v, off);
        if (tid == 0) {
          const float logit = v + bl[0];
          out[0] = 1.0f / (1.0f + __builtin_amdgcn_exp2f(-logit * L2E));
        }
      }
    }
  }
}

extern "C" void kernel_launch(void* const* d_in, const int* in_sizes, int n_in,
                              void* d_out, int out_size, void* d_ws,
                              size_t ws_size, hipStream_t stream)
{
  const float* x     = (const float*)d_in[0];
  const float* alpha = (const float*)d_in[1];
  const float* W1    = (const float*)d_in[2];
  const float* b1    = (const float*)d_in[3];
  const float* wt1   = (const float*)d_in[4];
  const float* bs1   = (const float*)d_in[5];
  const float* W2    = (const float*)d_in[6];
  const float* b2    = (const float*)d_in[7];
  const float* wt2   = (const float*)d_in[8];
  const float* bs2   = (const float*)d_in[9];
  const float* Wl    = (const float*)d_in[10];
  const float* bl    = (const float*)d_in[11];
  float* out = (float*)d_out;

  char* ws = (char*)d_ws;
  size_t off = 0;
  auto alloc = [&](size_t bytes) {
    void* p = ws + off;
    off = (off + bytes + 255) & ~(size_t)255;
    return p;
  };
  float* eta_s   = (float*)alloc(NN * 4 + 512);
  float* phi_s   = (float*)alloc(NN * 4 + 512);
  float* H1      = (float*)alloc((size_t)NN * 64 * 4);
  float* H2      = (float*)alloc((size_t)NN * 64 * 4);
  _Float16* HT1  = (_Float16*)alloc((size_t)NN * 64 * 2 + 512);
  _Float16* HT2  = (_Float16*)alloc((size_t)NN * 64 * 2 + 512);
  float* Yacc1   = (float*)alloc((size_t)NN * 64 * 4);
  float* Yacc2   = (float*)alloc((size_t)NN * 64 * 4);
  float* lsum    = (float*)alloc(NN * 4);
  float* svec    = (float*)alloc(64 * 4);
  unsigned* tick1 = (unsigned*)alloc(256 * 4);
  unsigned* tick2 = (unsigned*)alloc(256 * 4);
  unsigned* bar   = (unsigned*)alloc(256);

  prep_kernel<<<256, 256, 0, stream>>>(x, alpha, W1, b1, eta_s, phi_s, H1,
                                       HT1, lsum, Yacc1, Yacc2, svec, tick1,
                                       tick2, bar);
  fused_pass<1><<<1024, 256, 0, stream>>>(eta_s, phi_s, HT1, H1, wt1, bs1,
                                          W2, b2, alpha, lsum, Yacc1, H2,
                                          HT2, nullptr, nullptr, nullptr,
                                          nullptr, tick1, nullptr);
  fused_pass<2><<<1024, 256, 0, stream>>>(eta_s, phi_s, HT2, H2, wt2, bs2,
                                          nullptr, nullptr, alpha, lsum,
                                          Yacc2, nullptr, nullptr, svec, Wl,
                                          bl, out, tick2, bar);
}